// Round 7
// baseline (3344.446 us; speedup 1.0000x reference)
//
#include <hip/hip_runtime.h>

// ---------------------------------------------------------------------------
// E-GraphSAGE forward, f32. Stages:
//   1. CSR build by dst (histogram + scan + fill)
//   2. agg1 [N,80]  = mean over incoming edges of [x[src](16) | ea(64)]
//   3. h1  [N,128]  = ReLU([x | agg1] @ W1 + b1)          (K=96)
//   4. agg2 [N,192] = mean over incoming edges of [h1[src](128) | ea(64)]
//   5. h2  [N,128]  = ReLU([h1 | agg2] @ W2 + b2)         (K=320)
//   6. out [E,1]    = fused edge MLP 320->128->64->1, lane-owns-edge,
//                     weights via scalar(SGPR) loads -> VALU-bound
// ---------------------------------------------------------------------------

#define SCAN_T 1024

// edge_index may arrive as int32 or int64 depending on harness conversion.
__device__ __forceinline__ int ld_idx(const void* ei, long long pos, int is64) {
    if (is64) return (int)((const long long*)ei)[pos];
    return ((const int*)ei)[pos];
}

__global__ void detect64_kernel(const void* ei, int* flag) {
    if (threadIdx.x == 0 && blockIdx.x == 0) {
        const int* p = (const int*)ei;
        int is64 = 1;
        for (int i = 0; i < 64; ++i) {
            if (p[2 * i + 1] != 0) { is64 = 0; break; }
        }
        *flag = is64;
    }
}

__global__ void hist_kernel(const void* ei, int E, int* cnt, const int* flag) {
    int is64 = *flag;
    for (int e = blockIdx.x * blockDim.x + threadIdx.x; e < E;
         e += gridDim.x * blockDim.x) {
        int d = ld_idx(ei, (long long)E + e, is64);
        atomicAdd(&cnt[d], 1);
    }
}

__global__ void scan_kernel(const int* cnt, int* row, int n) {
    __shared__ int ps[SCAN_T];
    int tid = threadIdx.x;
    int per = (n + SCAN_T - 1) / SCAN_T;
    int s0 = tid * per;
    int s1 = min(s0 + per, n);
    int s = 0;
    for (int i = s0; i < s1; ++i) s += cnt[i];
    ps[tid] = s;
    __syncthreads();
    for (int off = 1; off < SCAN_T; off <<= 1) {
        int v = (tid >= off) ? ps[tid - off] : 0;
        __syncthreads();
        ps[tid] += v;
        __syncthreads();
    }
    int run = (tid == 0) ? 0 : ps[tid - 1];
    for (int i = s0; i < s1; ++i) { row[i] = run; run += cnt[i]; }
    if (s0 < n && s1 == n) row[n] = run;
}

__global__ void fill_kernel(const void* ei, int E, const int* row, int* cursor,
                            int* eids, const int* flag) {
    int is64 = *flag;
    for (int e = blockIdx.x * blockDim.x + threadIdx.x; e < E;
         e += gridDim.x * blockDim.x) {
        int d = ld_idx(ei, (long long)E + e, is64);
        int pos = atomicAdd(&cursor[d], 1);
        eids[row[d] + pos] = e;
    }
}

__global__ void agg1_kernel(const void* ei, const float* __restrict__ x,
                            const float* __restrict__ ea, const int* row,
                            const int* eids, float* __restrict__ agg1, int N,
                            const int* flag) {
    int is64 = *flag;
    int node = blockIdx.x * 4 + (threadIdx.x >> 6);
    int lane = threadIdx.x & 63;
    if (node >= N) return;
    int r0 = row[node], r1 = row[node + 1];
    float a0 = 0.f, a1 = 0.f;
    for (int i = r0; i < r1; ++i) {
        int e = eids[i];
        int s = ld_idx(ei, e, is64);
        float v0 = (lane < 16) ? x[s * 16 + lane] : ea[e * 64 + (lane - 16)];
        a0 += v0;
        if (lane < 16) a1 += ea[e * 64 + 48 + lane];
    }
    agg1[node * 80 + lane] = a0;
    if (lane < 16) agg1[node * 80 + 64 + lane] = a1;
}

__global__ void update1_kernel(const float* __restrict__ x,
                               const float* __restrict__ agg1, const int* row,
                               const float* __restrict__ W1,
                               const float* __restrict__ b1,
                               float* __restrict__ h1, int N) {
    __shared__ float in_s[8][96];
    int base = blockIdx.x * 8;
    int tid = threadIdx.x;
    for (int idx = tid; idx < 8 * 96; idx += 128) {
        int i = idx / 96, k = idx % 96;
        int node = base + i;
        float v = 0.f;
        if (node < N) {
            if (k < 16) v = x[node * 16 + k];
            else {
                float inv = 1.f / fmaxf((float)(row[node + 1] - row[node]), 1.f);
                v = agg1[node * 80 + (k - 16)] * inv;
            }
        }
        in_s[i][k] = v;
    }
    __syncthreads();
    int j = tid;
    float acc[8];
#pragma unroll
    for (int i = 0; i < 8; ++i) acc[i] = 0.f;
    for (int k = 0; k < 96; ++k) {
        float w = W1[k * 128 + j];
#pragma unroll
        for (int i = 0; i < 8; ++i) acc[i] += in_s[i][k] * w;
    }
    float bj = b1[j];
#pragma unroll
    for (int i = 0; i < 8; ++i) {
        int node = base + i;
        if (node < N) h1[node * 128 + j] = fmaxf(acc[i] + bj, 0.f);
    }
}

__global__ void agg2_kernel(const void* ei, const float* __restrict__ h1,
                            const float* __restrict__ ea, const int* row,
                            const int* eids, float* __restrict__ agg2, int N,
                            const int* flag) {
    int is64 = *flag;
    int node = blockIdx.x * 4 + (threadIdx.x >> 6);
    int lane = threadIdx.x & 63;
    if (node >= N) return;
    int r0 = row[node], r1 = row[node + 1];
    float a0 = 0.f, a1 = 0.f, a2 = 0.f;
    for (int i = r0; i < r1; ++i) {
        int e = eids[i];
        int s = ld_idx(ei, e, is64);
        a0 += h1[s * 128 + lane];
        a1 += h1[s * 128 + 64 + lane];
        a2 += ea[e * 64 + lane];
    }
    agg2[node * 192 + lane] = a0;
    agg2[node * 192 + 64 + lane] = a1;
    agg2[node * 192 + 128 + lane] = a2;
}

__global__ void update2_kernel(const float* __restrict__ h1,
                               const float* __restrict__ agg2, const int* row,
                               const float* __restrict__ W2,
                               const float* __restrict__ b2,
                               float* __restrict__ h2, int N) {
    __shared__ float in_s[8][320];
    int base = blockIdx.x * 8;
    int tid = threadIdx.x;
    for (int idx = tid; idx < 8 * 320; idx += 128) {
        int i = idx / 320, k = idx % 320;
        int node = base + i;
        float v = 0.f;
        if (node < N) {
            if (k < 128) v = h1[node * 128 + k];
            else {
                float inv = 1.f / fmaxf((float)(row[node + 1] - row[node]), 1.f);
                v = agg2[node * 192 + (k - 128)] * inv;
            }
        }
        in_s[i][k] = v;
    }
    __syncthreads();
    int j = tid;
    float acc[8];
#pragma unroll
    for (int i = 0; i < 8; ++i) acc[i] = 0.f;
    for (int k = 0; k < 320; ++k) {
        float w = W2[k * 128 + j];
#pragma unroll
        for (int i = 0; i < 8; ++i) acc[i] += in_s[i][k] * w;
    }
    float bj = b2[j];
#pragma unroll
    for (int i = 0; i < 8; ++i) {
        int node = base + i;
        if (node < N) h2[node * 128 + j] = fmaxf(acc[i] + bj, 0.f);
    }
}

// ---------------------------------------------------------------------------
// Fused edge classifier: 64 edges/block, 256 threads (4 waves).
// lane = edge; wave w owns an output-column strip. Weights are read with
// wave-uniform indices (readfirstlane) -> scalar s_load broadcasts, so the
// inner loop is 1 ds_read_b32 + 32 v_fmac(SGPR operand) per k.
// Phase A: z1[64][128] = ReLU(rep @ Wc1 + bc1)  (wave strip = 32 cols)
// Phase B: z2[64][64]  = ReLU(z1 @ Wc2 + bc2)   (wave strip = 16 cols)
// Phase C: out = z2 @ Wc3 + bc3 (per-wave partial + LDS cross-wave reduce)
// ---------------------------------------------------------------------------
__global__ __launch_bounds__(256, 3) void classifier_kernel(
    const void* ei, const float* __restrict__ h2, const float* __restrict__ ea,
    const float* __restrict__ Wc1, const float* __restrict__ bc1,
    const float* __restrict__ Wc2, const float* __restrict__ bc2,
    const float* __restrict__ Wc3, const float* __restrict__ bc3,
    float* __restrict__ out, int E, const int* flag) {
    __shared__ float rT[32][68];        // 8.7 KB  rep^T K-tile
    __shared__ float z1s[64 * 129];     // 33 KB   z1, stride 129 (bank=(e+c)%32)
    __shared__ float ps[64 * 5];        // 1.3 KB  phase-C partials, stride 5

    const int tid = threadIdx.x;
    const int base = blockIdx.x * 64;
    const int is64 = *flag;
    const int lane = tid & 63;                                  // edge slot
    const int wu = __builtin_amdgcn_readfirstlane(tid >> 6);    // wave 0..3
    const int kk0 = (tid >> 6) * 8;                             // staging k-seg
    const int eg = min(base + lane, E - 1);                     // staged edge

    // ---------------- Phase A: cols [32*wu, 32*wu+32) ----------------
    float acc[32];
#pragma unroll
    for (int j = 0; j < 32; ++j) acc[j] = 0.f;

    const float* WA = Wc1 + wu * 32;   // wave's column strip

    for (int kt = 0; kt < 10; ++kt) {
        const int kbase = kt * 32;
        // stage rep^T: this wave's 8-k segment for 64 edges
        {
            const int kb = kbase + kk0;
            const float* p;
            if (kb < 128) {
                int s = ld_idx(ei, eg, is64);
                p = h2 + (size_t)s * 128 + kb;
            } else if (kb < 256) {
                int d = ld_idx(ei, (long long)E + eg, is64);
                p = h2 + (size_t)d * 128 + (kb - 128);
            } else {
                p = ea + (size_t)eg * 64 + (kb - 256);
            }
            float4 v0 = *(const float4*)p;
            float4 v1 = *(const float4*)(p + 4);
            rT[kk0 + 0][lane] = v0.x; rT[kk0 + 1][lane] = v0.y;
            rT[kk0 + 2][lane] = v0.z; rT[kk0 + 3][lane] = v0.w;
            rT[kk0 + 4][lane] = v1.x; rT[kk0 + 5][lane] = v1.y;
            rT[kk0 + 6][lane] = v1.z; rT[kk0 + 7][lane] = v1.w;
        }
        __syncthreads();
#pragma unroll 4
        for (int kk = 0; kk < 32; ++kk) {
            float v = rT[kk][lane];                       // per-lane b32
            const float* wrow = WA + (size_t)(kbase + kk) * 128;  // uniform
#pragma unroll
            for (int j = 0; j < 32; ++j)
                acc[j] = fmaf(v, wrow[j], acc[j]);        // s_load operand
        }
        __syncthreads();
    }
    // epilogue A: bias + ReLU -> z1s (stride 129: bank=(e+c)%32, no conflict)
    {
        const float* bA = bc1 + wu * 32;
#pragma unroll
        for (int j = 0; j < 32; ++j)
            z1s[lane * 129 + wu * 32 + j] = fmaxf(acc[j] + bA[j], 0.f);
    }
    __syncthreads();

    // ---------------- Phase B: cols [16*wu, 16*wu+16) ----------------
    float acc2[16];
#pragma unroll
    for (int j = 0; j < 16; ++j) acc2[j] = 0.f;
    const float* WB = Wc2 + wu * 16;
#pragma unroll 4
    for (int kk = 0; kk < 128; ++kk) {
        float v = z1s[lane * 129 + kk];
        const float* wrow = WB + (size_t)kk * 64;         // uniform
#pragma unroll
        for (int j = 0; j < 16; ++j)
            acc2[j] = fmaf(v, wrow[j], acc2[j]);
    }
    // bias + ReLU in regs
    {
        const float* bB = bc2 + wu * 16;
#pragma unroll
        for (int j = 0; j < 16; ++j)
            acc2[j] = fmaxf(acc2[j] + bB[j], 0.f);
    }

    // ---------------- Phase C ----------------
    {
        const float* WC = Wc3 + wu * 16;                  // uniform
        float p = 0.f;
#pragma unroll
        for (int j = 0; j < 16; ++j) p = fmaf(acc2[j], WC[j], p);
        ps[lane * 5 + wu] = p;
    }
    __syncthreads();
    if (wu == 0) {
        float r = ps[lane * 5 + 0] + ps[lane * 5 + 1] + ps[lane * 5 + 2] +
                  ps[lane * 5 + 3] + bc3[0];
        if (base + lane < E) out[base + lane] = r;
    }
}

extern "C" void kernel_launch(void* const* d_in, const int* in_sizes, int n_in,
                              void* d_out, int out_size, void* d_ws,
                              size_t ws_size, hipStream_t stream) {
    const float* x   = (const float*)d_in[0];
    const void*  ei  = d_in[1];
    const float* ea  = (const float*)d_in[2];
    const float* W1  = (const float*)d_in[3];
    const float* b1  = (const float*)d_in[4];
    const float* W2  = (const float*)d_in[5];
    const float* b2  = (const float*)d_in[6];
    const float* Wc1 = (const float*)d_in[7];
    const float* bc1 = (const float*)d_in[8];
    const float* Wc2 = (const float*)d_in[9];
    const float* bc2 = (const float*)d_in[10];
    const float* Wc3 = (const float*)d_in[11];
    const float* bc3 = (const float*)d_in[12];
    float* out = (float*)d_out;

    int N = in_sizes[0] / 16;   // 50000
    int E = in_sizes[2] / 64;   // 800000

    char* ws = (char*)d_ws;
    size_t off = 0;
    auto alloc = [&](size_t bytes) {
        void* p = ws + off;
        off += (bytes + 511) & ~(size_t)511;
        return p;
    };
    int*   cnt    = (int*)alloc((size_t)N * 4);
    int*   cursor = (int*)alloc((size_t)N * 4);
    int*   row    = (int*)alloc((size_t)(N + 1) * 4);
    int*   eids   = (int*)alloc((size_t)E * 4);
    int*   flag   = (int*)alloc(4);
    float* agg1   = (float*)alloc((size_t)N * 80 * 4);
    float* h1     = (float*)alloc((size_t)N * 128 * 4);
    float* agg2   = (float*)alloc((size_t)N * 192 * 4);
    float* h2     = (float*)alloc((size_t)N * 128 * 4);
    (void)ws_size; (void)n_in; (void)out_size;

    hipMemsetAsync(cnt, 0, (size_t)N * 4, stream);
    hipMemsetAsync(cursor, 0, (size_t)N * 4, stream);

    detect64_kernel<<<1, 64, 0, stream>>>(ei, flag);
    hist_kernel<<<1024, 256, 0, stream>>>(ei, E, cnt, flag);
    scan_kernel<<<1, SCAN_T, 0, stream>>>(cnt, row, N);
    fill_kernel<<<1024, 256, 0, stream>>>(ei, E, row, cursor, eids, flag);
    agg1_kernel<<<(N + 3) / 4, 256, 0, stream>>>(ei, x, ea, row, eids, agg1, N, flag);
    update1_kernel<<<(N + 7) / 8, 128, 0, stream>>>(x, agg1, row, W1, b1, h1, N);
    agg2_kernel<<<(N + 3) / 4, 256, 0, stream>>>(ei, h1, ea, row, eids, agg2, N, flag);
    update2_kernel<<<(N + 7) / 8, 128, 0, stream>>>(h1, agg2, row, W2, b2, h2, N);
    classifier_kernel<<<(E + 63) / 64, 256, 0, stream>>>(ei, h2, ea, Wc1, bc1,
                                                         Wc2, bc2, Wc3, bc3,
                                                         out, E, flag);
}

// Round 10
// 1527.675 us; speedup vs baseline: 2.1892x; 2.1892x over previous
//
#include <hip/hip_runtime.h>

// ---------------------------------------------------------------------------
// E-GraphSAGE forward. Stages:
//   1. CSR build by dst (histogram + scan + fill)
//   2. agg1 [N,80]  = mean over incoming edges of [x[src](16) | ea(64)]
//   3. h1  [N,128]  = ReLU([x | agg1] @ W1 + b1)          (K=96)   f32
//   4. agg2 [N,192] = mean over incoming edges of [h1[src](128) | ea(64)]
//   5. h2b [N,128]  = ReLU([h1 | agg2] @ W2 + b2) -> bf16 (K=320)
//   6. out [E,1]    = edge MLP 320->128->64->1 via bf16 MFMA, f32 accum
// ---------------------------------------------------------------------------

#define SCAN_T 1024

typedef __attribute__((ext_vector_type(8))) short bf16x8;
typedef __attribute__((ext_vector_type(4))) float f32x4;

__device__ __forceinline__ unsigned short f2b(float f) {   // f32 -> bf16 RNE
    unsigned int u = __builtin_bit_cast(unsigned int, f);
    u += 0x7fffu + ((u >> 16) & 1u);
    return (unsigned short)(u >> 16);
}

// edge_index may arrive as int32 or int64 depending on harness conversion.
__device__ __forceinline__ int ld_idx(const void* ei, long long pos, int is64) {
    if (is64) return (int)((const long long*)ei)[pos];
    return ((const int*)ei)[pos];
}

__global__ void detect64_kernel(const void* ei, int* flag) {
    if (threadIdx.x == 0 && blockIdx.x == 0) {
        const int* p = (const int*)ei;
        int is64 = 1;
        for (int i = 0; i < 64; ++i) {
            if (p[2 * i + 1] != 0) { is64 = 0; break; }
        }
        *flag = is64;
    }
}

// Wc1[320][128] -> WT1[128][320] bf16 ; Wc2[128][64] -> WT2[64][128] bf16
__global__ void prep_w_kernel(const float* __restrict__ Wc1,
                              const float* __restrict__ Wc2,
                              unsigned short* __restrict__ WT1,
                              unsigned short* __restrict__ WT2) {
    int i = blockIdx.x * 256 + threadIdx.x;
    if (i < 320 * 128) { int k = i >> 7, n = i & 127; WT1[n * 320 + k] = f2b(Wc1[i]); }
    if (i < 128 * 64)  { int k = i >> 6, n = i & 63;  WT2[n * 128 + k] = f2b(Wc2[i]); }
}

__global__ void hist_kernel(const void* ei, int E, int* cnt, const int* flag) {
    int is64 = *flag;
    for (int e = blockIdx.x * blockDim.x + threadIdx.x; e < E;
         e += gridDim.x * blockDim.x) {
        int d = ld_idx(ei, (long long)E + e, is64);
        atomicAdd(&cnt[d], 1);
    }
}

__global__ void scan_kernel(const int* cnt, int* row, int n) {
    __shared__ int ps[SCAN_T];
    int tid = threadIdx.x;
    int per = (n + SCAN_T - 1) / SCAN_T;
    int s0 = tid * per;
    int s1 = min(s0 + per, n);
    int s = 0;
    for (int i = s0; i < s1; ++i) s += cnt[i];
    ps[tid] = s;
    __syncthreads();
    for (int off = 1; off < SCAN_T; off <<= 1) {
        int v = (tid >= off) ? ps[tid - off] : 0;
        __syncthreads();
        ps[tid] += v;
        __syncthreads();
    }
    int run = (tid == 0) ? 0 : ps[tid - 1];
    for (int i = s0; i < s1; ++i) { row[i] = run; run += cnt[i]; }
    if (s0 < n && s1 == n) row[n] = run;
}

__global__ void fill_kernel(const void* ei, int E, const int* row, int* cursor,
                            int* eids, const int* flag) {
    int is64 = *flag;
    for (int e = blockIdx.x * blockDim.x + threadIdx.x; e < E;
         e += gridDim.x * blockDim.x) {
        int d = ld_idx(ei, (long long)E + e, is64);
        int pos = atomicAdd(&cursor[d], 1);
        eids[row[d] + pos] = e;
    }
}

__global__ void agg1_kernel(const void* ei, const float* __restrict__ x,
                            const float* __restrict__ ea, const int* row,
                            const int* eids, float* __restrict__ agg1, int N,
                            const int* flag) {
    int is64 = *flag;
    int node = blockIdx.x * 4 + (threadIdx.x >> 6);
    int lane = threadIdx.x & 63;
    if (node >= N) return;
    int r0 = row[node], r1 = row[node + 1];
    float a0 = 0.f, a1 = 0.f;
    for (int i = r0; i < r1; ++i) {
        int e = eids[i];
        int s = ld_idx(ei, e, is64);
        float v0 = (lane < 16) ? x[s * 16 + lane] : ea[e * 64 + (lane - 16)];
        a0 += v0;
        if (lane < 16) a1 += ea[e * 64 + 48 + lane];
    }
    agg1[node * 80 + lane] = a0;
    if (lane < 16) agg1[node * 80 + 64 + lane] = a1;
}

__global__ void update1_kernel(const float* __restrict__ x,
                               const float* __restrict__ agg1, const int* row,
                               const float* __restrict__ W1,
                               const float* __restrict__ b1,
                               float* __restrict__ h1, int N) {
    __shared__ float in_s[8][96];
    int base = blockIdx.x * 8;
    int tid = threadIdx.x;
    for (int idx = tid; idx < 8 * 96; idx += 128) {
        int i = idx / 96, k = idx % 96;
        int node = base + i;
        float v = 0.f;
        if (node < N) {
            if (k < 16) v = x[node * 16 + k];
            else {
                float inv = 1.f / fmaxf((float)(row[node + 1] - row[node]), 1.f);
                v = agg1[node * 80 + (k - 16)] * inv;
            }
        }
        in_s[i][k] = v;
    }
    __syncthreads();
    int j = tid;
    float acc[8];
#pragma unroll
    for (int i = 0; i < 8; ++i) acc[i] = 0.f;
    for (int k = 0; k < 96; ++k) {
        float w = W1[k * 128 + j];
#pragma unroll
        for (int i = 0; i < 8; ++i) acc[i] += in_s[i][k] * w;
    }
    float bj = b1[j];
#pragma unroll
    for (int i = 0; i < 8; ++i) {
        int node = base + i;
        if (node < N) h1[node * 128 + j] = fmaxf(acc[i] + bj, 0.f);
    }
}

__global__ void agg2_kernel(const void* ei, const float* __restrict__ h1,
                            const float* __restrict__ ea, const int* row,
                            const int* eids, float* __restrict__ agg2, int N,
                            const int* flag) {
    int is64 = *flag;
    int node = blockIdx.x * 4 + (threadIdx.x >> 6);
    int lane = threadIdx.x & 63;
    if (node >= N) return;
    int r0 = row[node], r1 = row[node + 1];
    float a0 = 0.f, a1 = 0.f, a2 = 0.f;
    for (int i = r0; i < r1; ++i) {
        int e = eids[i];
        int s = ld_idx(ei, e, is64);
        a0 += h1[s * 128 + lane];
        a1 += h1[s * 128 + 64 + lane];
        a2 += ea[e * 64 + lane];
    }
    agg2[node * 192 + lane] = a0;
    agg2[node * 192 + 64 + lane] = a1;
    agg2[node * 192 + 128 + lane] = a2;
}

// h2 written as bf16 (halves classifier gather traffic; threshold is bf16-tolerant)
__global__ void update2_kernel(const float* __restrict__ h1,
                               const float* __restrict__ agg2, const int* row,
                               const float* __restrict__ W2,
                               const float* __restrict__ b2,
                               unsigned short* __restrict__ h2b, int N) {
    __shared__ float in_s[8][320];
    int base = blockIdx.x * 8;
    int tid = threadIdx.x;
    for (int idx = tid; idx < 8 * 320; idx += 128) {
        int i = idx / 320, k = idx % 320;
        int node = base + i;
        float v = 0.f;
        if (node < N) {
            if (k < 128) v = h1[node * 128 + k];
            else {
                float inv = 1.f / fmaxf((float)(row[node + 1] - row[node]), 1.f);
                v = agg2[node * 192 + (k - 128)] * inv;
            }
        }
        in_s[i][k] = v;
    }
    __syncthreads();
    int j = tid;
    float acc[8];
#pragma unroll
    for (int i = 0; i < 8; ++i) acc[i] = 0.f;
    for (int k = 0; k < 320; ++k) {
        float w = W2[k * 128 + j];
#pragma unroll
        for (int i = 0; i < 8; ++i) acc[i] += in_s[i][k] * w;
    }
    float bj = b2[j];
#pragma unroll
    for (int i = 0; i < 8; ++i) {
        int node = base + i;
        if (node < N) h2b[node * 128 + j] = f2b(fmaxf(acc[i] + bj, 0.f));
    }
}

// ---------------------------------------------------------------------------
// MFMA edge classifier. 64 edges/block, 256 threads (4 waves).
// Wave w owns edges [16w,16w+16). Phase A: 8 n-tiles x 10 k-steps of
// mfma_f32_16x16x32_bf16 (C/D: col=lane&15, row=(lane>>4)*4+reg).
// A/B frags: 8 contiguous-k bf16 per lane (consistent k-map cancels).
// NOTE: uint4 = 16 BYTES = 8 bf16. Each W1 k-row (32 shorts) needs 4 uint4s;
// staging covers shorts [16h,16h+16) per (c,h) via two uint4 stores.
// LDS regions (62464 B total, 2 blocks/CU):
//   [0..41984)    repb[64][328]  -> (after A) z1b[64][136], z2b[64][72], psum
//   [41984..62464) wt[2][128][40] -> (after A) w2t[64][136]
// ---------------------------------------------------------------------------
__global__ __launch_bounds__(256, 2) void classifier_mfma(
    const void* ei, const unsigned short* __restrict__ h2b,
    const float* __restrict__ ea,
    const unsigned short* __restrict__ WT1, const float* __restrict__ bc1,
    const unsigned short* __restrict__ WT2, const float* __restrict__ bc2,
    const float* __restrict__ Wc3, const float* __restrict__ bc3,
    float* __restrict__ out, int E, const int* flag) {
    __shared__ __align__(16) char smem[62464];
    unsigned short* repb = (unsigned short*)smem;            // [64][328]
    unsigned short* z1b  = (unsigned short*)smem;            // [64][136]
    unsigned short* z2b  = (unsigned short*)(smem + 17408);  // [64][72]
    float*          psum = (float*)(smem + 26624);           // [64][5]
    unsigned short* wt   = (unsigned short*)(smem + 41984);  // [2][128][40]
    unsigned short* w2t  = (unsigned short*)(smem + 41984);  // [64][136]

    const int tid = threadIdx.x;
    const int base = blockIdx.x * 64;
    const int is64 = *flag;
    const int l  = tid & 63;
    const int w  = tid >> 6;
    const int lm = l & 15;   // m/n index within 16x16 tile
    const int g  = l >> 4;   // k-group (frag k0 = 8*g)

    // ---- stage rep[64][320] as bf16 (k<256 from h2b, k>=256 from ea f32) ----
    for (int idx = tid; idx < 64 * 160; idx += 256) {
        int e  = idx / 160;
        int kp = idx - e * 160;
        int k2 = kp * 2;
        int eg = min(base + e, E - 1);
        unsigned int u;
        if (k2 < 256) {
            long long nidx = (k2 < 128) ? (long long)ld_idx(ei, eg, is64)
                                        : (long long)ld_idx(ei, (long long)E + eg, is64);
            u = *(const unsigned int*)(h2b + (size_t)nidx * 128 + (k2 & 127));
        } else {
            float2 v = *(const float2*)(ea + (size_t)eg * 64 + (k2 - 256));
            u = (unsigned int)f2b(v.x) | ((unsigned int)f2b(v.y) << 16);
        }
        *(unsigned int*)(repb + e * 328 + k2) = u;
    }
    // ---- stage W-tile for kt=0 (16 shorts per (c,h) = 2 x uint4) ----
    {
        int c = tid >> 1, h = tid & 1;
        const unsigned short* src = WT1 + (size_t)c * 320 + 16 * h;
        unsigned short* dst = wt + c * 40 + 16 * h;
        uint4 v0 = *(const uint4*)src;
        uint4 v1 = *(const uint4*)(src + 8);
        *(uint4*)dst = v0;
        *(uint4*)(dst + 8) = v1;
    }
    __syncthreads();

    // ---- Phase A: z1[64][128], K=320 ----
    f32x4 zero = {0.f, 0.f, 0.f, 0.f};
    f32x4 acc[8];
#pragma unroll
    for (int n = 0; n < 8; ++n) acc[n] = zero;

    const int arow = (16 * w + lm) * 328;
    for (int kt = 0; kt < 10; ++kt) {
        const int cur = kt & 1;
        if (kt < 9) {   // prefetch next W-tile into other buffer
            int c = tid >> 1, h = tid & 1;
            const unsigned short* src = WT1 + (size_t)c * 320 + (kt + 1) * 32 + 16 * h;
            unsigned short* dst = wt + (cur ^ 1) * 5120 + c * 40 + 16 * h;
            uint4 v0 = *(const uint4*)src;
            uint4 v1 = *(const uint4*)(src + 8);
            *(uint4*)dst = v0;
            *(uint4*)(dst + 8) = v1;
        }
        bf16x8 a = *(const bf16x8*)(repb + arow + kt * 32 + g * 8);
        const unsigned short* wb = wt + cur * 5120 + g * 8;
#pragma unroll
        for (int n = 0; n < 8; ++n) {
            bf16x8 b = *(const bf16x8*)(wb + (16 * n + lm) * 40);
            acc[n] = __builtin_amdgcn_mfma_f32_16x16x32_bf16(a, b, acc[n], 0, 0, 0);
        }
        __syncthreads();
    }

    // ---- epilogue A: bias+ReLU -> z1b (aliases repb; reads done pre-barrier) ----
#pragma unroll
    for (int n = 0; n < 8; ++n) {
        float bj = bc1[16 * n + lm];
#pragma unroll
        for (int r = 0; r < 4; ++r) {
            float v = fmaxf(acc[n][r] + bj, 0.f);
            z1b[(16 * w + g * 4 + r) * 136 + 16 * n + lm] = f2b(v);
        }
    }
    // ---- stage W2 [64][128] -> w2t (aliases wt; reads done pre-barrier) ----
    {
        int c = tid >> 2, q = tid & 3;
#pragma unroll
        for (int j = 0; j < 4; ++j) {
            uint4 v = *(const uint4*)(WT2 + (size_t)c * 128 + q * 32 + j * 8);
            *(uint4*)(w2t + c * 136 + q * 32 + j * 8) = v;
        }
    }
    __syncthreads();

    // ---- Phase B: z2[64][64], K=128 ----
    f32x4 acc2[4];
#pragma unroll
    for (int n = 0; n < 4; ++n) acc2[n] = zero;
    const int brow = (16 * w + lm) * 136;
#pragma unroll
    for (int kt = 0; kt < 4; ++kt) {
        bf16x8 a = *(const bf16x8*)(z1b + brow + kt * 32 + g * 8);
#pragma unroll
        for (int n = 0; n < 4; ++n) {
            bf16x8 b = *(const bf16x8*)(w2t + (16 * n + lm) * 136 + kt * 32 + g * 8);
            acc2[n] = __builtin_amdgcn_mfma_f32_16x16x32_bf16(a, b, acc2[n], 0, 0, 0);
        }
    }
    // ---- epilogue B: bias+ReLU -> z2b ----
#pragma unroll
    for (int n = 0; n < 4; ++n) {
        float bj = bc2[16 * n + lm];
#pragma unroll
        for (int r = 0; r < 4; ++r) {
            float v = fmaxf(acc2[n][r] + bj, 0.f);
            z2b[(16 * w + g * 4 + r) * 72 + 16 * n + lm] = f2b(v);
        }
    }
    __syncthreads();

    // ---- Phase C: out = z2 @ Wc3 + bc3 (f32) ----
    {
        int e = tid & 63, seg = tid >> 6;
        const uint4* zp = (const uint4*)(z2b + e * 72 + seg * 16);
        uint4 v0 = zp[0], v1 = zp[1];
        unsigned int vv[8] = {v0.x, v0.y, v0.z, v0.w, v1.x, v1.y, v1.z, v1.w};
        float p = 0.f;
#pragma unroll
        for (int i = 0; i < 8; ++i) {
            float lo = __builtin_bit_cast(float, vv[i] << 16);
            float hi = __builtin_bit_cast(float, vv[i] & 0xffff0000u);
            p += lo * Wc3[seg * 16 + 2 * i] + hi * Wc3[seg * 16 + 2 * i + 1];
        }
        psum[e * 5 + seg] = p;
    }
    __syncthreads();
    if (w == 0) {
        float r = psum[l * 5 + 0] + psum[l * 5 + 1] + psum[l * 5 + 2] +
                  psum[l * 5 + 3] + bc3[0];
        if (base + l < E) out[base + l] = r;
    }
}

extern "C" void kernel_launch(void* const* d_in, const int* in_sizes, int n_in,
                              void* d_out, int out_size, void* d_ws,
                              size_t ws_size, hipStream_t stream) {
    const float* x   = (const float*)d_in[0];
    const void*  ei  = d_in[1];
    const float* ea  = (const float*)d_in[2];
    const float* W1  = (const float*)d_in[3];
    const float* b1  = (const float*)d_in[4];
    const float* W2  = (const float*)d_in[5];
    const float* b2  = (const float*)d_in[6];
    const float* Wc1 = (const float*)d_in[7];
    const float* bc1 = (const float*)d_in[8];
    const float* Wc2 = (const float*)d_in[9];
    const float* bc2 = (const float*)d_in[10];
    const float* Wc3 = (const float*)d_in[11];
    const float* bc3 = (const float*)d_in[12];
    float* out = (float*)d_out;

    int N = in_sizes[0] / 16;   // 50000
    int E = in_sizes[2] / 64;   // 800000

    char* ws = (char*)d_ws;
    size_t off = 0;
    auto alloc = [&](size_t bytes) {
        void* p = ws + off;
        off += (bytes + 511) & ~(size_t)511;
        return p;
    };
    int*            cnt    = (int*)alloc((size_t)N * 4);
    int*            cursor = (int*)alloc((size_t)N * 4);
    int*            row    = (int*)alloc((size_t)(N + 1) * 4);
    int*            eids   = (int*)alloc((size_t)E * 4);
    int*            flag   = (int*)alloc(4);
    float*          agg1   = (float*)alloc((size_t)N * 80 * 4);
    float*          h1     = (float*)alloc((size_t)N * 128 * 4);
    float*          agg2   = (float*)alloc((size_t)N * 192 * 4);
    unsigned short* h2b    = (unsigned short*)alloc((size_t)N * 128 * 2);
    unsigned short* WT1    = (unsigned short*)alloc((size_t)128 * 320 * 2);
    unsigned short* WT2    = (unsigned short*)alloc((size_t)64 * 128 * 2);
    (void)ws_size; (void)n_in; (void)out_size;

    hipMemsetAsync(cnt, 0, (size_t)N * 4, stream);
    hipMemsetAsync(cursor, 0, (size_t)N * 4, stream);

    detect64_kernel<<<1, 64, 0, stream>>>(ei, flag);
    prep_w_kernel<<<160, 256, 0, stream>>>(Wc1, Wc2, WT1, WT2);
    hist_kernel<<<1024, 256, 0, stream>>>(ei, E, cnt, flag);
    scan_kernel<<<1, SCAN_T, 0, stream>>>(cnt, row, N);
    fill_kernel<<<1024, 256, 0, stream>>>(ei, E, row, cursor, eids, flag);
    agg1_kernel<<<(N + 3) / 4, 256, 0, stream>>>(ei, x, ea, row, eids, agg1, N, flag);
    update1_kernel<<<(N + 7) / 8, 128, 0, stream>>>(x, agg1, row, W1, b1, h1, N);
    agg2_kernel<<<(N + 3) / 4, 256, 0, stream>>>(ei, h1, ea, row, eids, agg2, N, flag);
    update2_kernel<<<(N + 7) / 8, 128, 0, stream>>>(h1, agg2, row, W2, b2, h2b, N);
    classifier_mfma<<<(E + 63) / 64, 256, 0, stream>>>(ei, h2b, ea, WT1, bc1,
                                                       WT2, bc2, Wc3, bc3,
                                                       out, E, flag);
}

// Round 11
// 768.511 us; speedup vs baseline: 4.3519x; 1.9878x over previous
//
#include <hip/hip_runtime.h>

// ---------------------------------------------------------------------------
// E-GraphSAGE forward. Stages:
//   1. CSR build by dst (histogram + scan + fill)
//   2. agg1 [N,80]  = mean over incoming edges of [x[src](16) | ea(64)]
//   3. h1  [N,128]  = ReLU([x | agg1] @ W1 + b1)          (K=96)   f32
//   4. agg2 [N,192] = mean over incoming edges of [h1[src](128) | ea(64)]
//   5. h2b [N,128]  = ReLU([h1 | agg2] @ W2 + b2) -> bf16 (K=320)
//   6. out [E,1]    = edge MLP 320->128->64->1, bf16 MFMA, persistent blocks:
//                     weights LDS-resident (staged once), A-frags gathered
//                     global->VGPR, no barriers in the k-loop.
// ---------------------------------------------------------------------------

#define SCAN_T 1024

typedef __attribute__((ext_vector_type(8))) short bf16x8;
typedef __attribute__((ext_vector_type(4))) float f32x4;

__device__ __forceinline__ unsigned short f2b(float f) {   // f32 -> bf16 RNE
    unsigned int u = __builtin_bit_cast(unsigned int, f);
    u += 0x7fffu + ((u >> 16) & 1u);
    return (unsigned short)(u >> 16);
}

// edge_index may arrive as int32 or int64 depending on harness conversion.
__device__ __forceinline__ int ld_idx(const void* ei, long long pos, int is64) {
    if (is64) return (int)((const long long*)ei)[pos];
    return ((const int*)ei)[pos];
}

__global__ void detect64_kernel(const void* ei, int* flag) {
    if (threadIdx.x == 0 && blockIdx.x == 0) {
        const int* p = (const int*)ei;
        int is64 = 1;
        for (int i = 0; i < 64; ++i) {
            if (p[2 * i + 1] != 0) { is64 = 0; break; }
        }
        *flag = is64;
    }
}

// Wc1[320][128] -> WT1[128][320] bf16 ; Wc2[128][64] -> WT2[64][128] bf16
__global__ void prep_w_kernel(const float* __restrict__ Wc1,
                              const float* __restrict__ Wc2,
                              unsigned short* __restrict__ WT1,
                              unsigned short* __restrict__ WT2) {
    int i = blockIdx.x * 256 + threadIdx.x;
    if (i < 320 * 128) { int k = i >> 7, n = i & 127; WT1[n * 320 + k] = f2b(Wc1[i]); }
    if (i < 128 * 64)  { int k = i >> 6, n = i & 63;  WT2[n * 128 + k] = f2b(Wc2[i]); }
}

__global__ void hist_kernel(const void* ei, int E, int* cnt, const int* flag) {
    int is64 = *flag;
    for (int e = blockIdx.x * blockDim.x + threadIdx.x; e < E;
         e += gridDim.x * blockDim.x) {
        int d = ld_idx(ei, (long long)E + e, is64);
        atomicAdd(&cnt[d], 1);
    }
}

__global__ void scan_kernel(const int* cnt, int* row, int n) {
    __shared__ int ps[SCAN_T];
    int tid = threadIdx.x;
    int per = (n + SCAN_T - 1) / SCAN_T;
    int s0 = tid * per;
    int s1 = min(s0 + per, n);
    int s = 0;
    for (int i = s0; i < s1; ++i) s += cnt[i];
    ps[tid] = s;
    __syncthreads();
    for (int off = 1; off < SCAN_T; off <<= 1) {
        int v = (tid >= off) ? ps[tid - off] : 0;
        __syncthreads();
        ps[tid] += v;
        __syncthreads();
    }
    int run = (tid == 0) ? 0 : ps[tid - 1];
    for (int i = s0; i < s1; ++i) { row[i] = run; run += cnt[i]; }
    if (s0 < n && s1 == n) row[n] = run;
}

__global__ void fill_kernel(const void* ei, int E, const int* row, int* cursor,
                            int* eids, const int* flag) {
    int is64 = *flag;
    for (int e = blockIdx.x * blockDim.x + threadIdx.x; e < E;
         e += gridDim.x * blockDim.x) {
        int d = ld_idx(ei, (long long)E + e, is64);
        int pos = atomicAdd(&cursor[d], 1);
        eids[row[d] + pos] = e;
    }
}

__global__ void agg1_kernel(const void* ei, const float* __restrict__ x,
                            const float* __restrict__ ea, const int* row,
                            const int* eids, float* __restrict__ agg1, int N,
                            const int* flag) {
    int is64 = *flag;
    int node = blockIdx.x * 4 + (threadIdx.x >> 6);
    int lane = threadIdx.x & 63;
    if (node >= N) return;
    int r0 = row[node], r1 = row[node + 1];
    float a0 = 0.f, a1 = 0.f;
    for (int i = r0; i < r1; ++i) {
        int e = eids[i];
        int s = ld_idx(ei, e, is64);
        float v0 = (lane < 16) ? x[s * 16 + lane] : ea[e * 64 + (lane - 16)];
        a0 += v0;
        if (lane < 16) a1 += ea[e * 64 + 48 + lane];
    }
    agg1[node * 80 + lane] = a0;
    if (lane < 16) agg1[node * 80 + 64 + lane] = a1;
}

__global__ void update1_kernel(const float* __restrict__ x,
                               const float* __restrict__ agg1, const int* row,
                               const float* __restrict__ W1,
                               const float* __restrict__ b1,
                               float* __restrict__ h1, int N) {
    __shared__ float in_s[8][96];
    int base = blockIdx.x * 8;
    int tid = threadIdx.x;
    for (int idx = tid; idx < 8 * 96; idx += 128) {
        int i = idx / 96, k = idx % 96;
        int node = base + i;
        float v = 0.f;
        if (node < N) {
            if (k < 16) v = x[node * 16 + k];
            else {
                float inv = 1.f / fmaxf((float)(row[node + 1] - row[node]), 1.f);
                v = agg1[node * 80 + (k - 16)] * inv;
            }
        }
        in_s[i][k] = v;
    }
    __syncthreads();
    int j = tid;
    float acc[8];
#pragma unroll
    for (int i = 0; i < 8; ++i) acc[i] = 0.f;
    for (int k = 0; k < 96; ++k) {
        float w = W1[k * 128 + j];
#pragma unroll
        for (int i = 0; i < 8; ++i) acc[i] += in_s[i][k] * w;
    }
    float bj = b1[j];
#pragma unroll
    for (int i = 0; i < 8; ++i) {
        int node = base + i;
        if (node < N) h1[node * 128 + j] = fmaxf(acc[i] + bj, 0.f);
    }
}

__global__ void agg2_kernel(const void* ei, const float* __restrict__ h1,
                            const float* __restrict__ ea, const int* row,
                            const int* eids, float* __restrict__ agg2, int N,
                            const int* flag) {
    int is64 = *flag;
    int node = blockIdx.x * 4 + (threadIdx.x >> 6);
    int lane = threadIdx.x & 63;
    if (node >= N) return;
    int r0 = row[node], r1 = row[node + 1];
    float a0 = 0.f, a1 = 0.f, a2 = 0.f;
    for (int i = r0; i < r1; ++i) {
        int e = eids[i];
        int s = ld_idx(ei, e, is64);
        a0 += h1[s * 128 + lane];
        a1 += h1[s * 128 + 64 + lane];
        a2 += ea[e * 64 + lane];
    }
    agg2[node * 192 + lane] = a0;
    agg2[node * 192 + 64 + lane] = a1;
    agg2[node * 192 + 128 + lane] = a2;
}

// h2 written as bf16 (halves classifier gather traffic; threshold is bf16-tolerant)
__global__ void update2_kernel(const float* __restrict__ h1,
                               const float* __restrict__ agg2, const int* row,
                               const float* __restrict__ W2,
                               const float* __restrict__ b2,
                               unsigned short* __restrict__ h2b, int N) {
    __shared__ float in_s[8][320];
    int base = blockIdx.x * 8;
    int tid = threadIdx.x;
    for (int idx = tid; idx < 8 * 320; idx += 128) {
        int i = idx / 320, k = idx % 320;
        int node = base + i;
        float v = 0.f;
        if (node < N) {
            if (k < 128) v = h1[node * 128 + k];
            else {
                float inv = 1.f / fmaxf((float)(row[node + 1] - row[node]), 1.f);
                v = agg2[node * 192 + (k - 128)] * inv;
            }
        }
        in_s[i][k] = v;
    }
    __syncthreads();
    int j = tid;
    float acc[8];
#pragma unroll
    for (int i = 0; i < 8; ++i) acc[i] = 0.f;
    for (int k = 0; k < 320; ++k) {
        float w = W2[k * 128 + j];
#pragma unroll
        for (int i = 0; i < 8; ++i) acc[i] += in_s[i][k] * w;
    }
    float bj = b2[j];
#pragma unroll
    for (int i = 0; i < 8; ++i) {
        int node = base + i;
        if (node < N) h2b[node * 128 + j] = f2b(fmaxf(acc[i] + bj, 0.f));
    }
}

// ---------------------------------------------------------------------------
// Persistent MFMA edge classifier. 256 blocks x 512 threads (8 waves),
// grid-stride over tiles of 128 edges. Wave w owns edges [16w,16w+16).
// Weights LDS-resident, frag-major: frag f=kt*4+g at [(f*J + j)*8] shorts ->
// wave b128 reads hit the 8-clk floor (bank slot = lm%8). A-frags gathered
// per-lane from global (h2b bf16 rows; ea f32 converted). MFMA mapping as
// validated in R10: C/D row(edge)=g*4+reg, col(j)=lm.
// LDS map (133120 B): wt1f[0,81920) wt2f[81920,98304) z1b[98304,133120)
//                     z2b aliases z1b[0,18432) psum at +18432 (2560 B)
// Barriers: 5/tile (top, post-eA, post-B-mfma, post-eB, post-psum).
// ---------------------------------------------------------------------------
__global__ __launch_bounds__(512, 1) void classifier_mfma(
    const void* ei, const unsigned short* __restrict__ h2b,
    const float* __restrict__ ea,
    const unsigned short* __restrict__ WT1, const float* __restrict__ bc1,
    const unsigned short* __restrict__ WT2, const float* __restrict__ bc2,
    const float* __restrict__ Wc3, const float* __restrict__ bc3,
    float* __restrict__ out, int E, const int* flag) {
    __shared__ __align__(16) char smem[133120];
    unsigned short* wt1f = (unsigned short*)smem;             // 40 frags x 128 j
    unsigned short* wt2f = (unsigned short*)(smem + 81920);   // 16 frags x 64 j
    unsigned short* z1b  = (unsigned short*)(smem + 98304);   // [128][136]
    unsigned short* z2b  = (unsigned short*)(smem + 98304);   // [128][72] alias
    float*          psum = (float*)(smem + 98304 + 18432);    // [128][5]

    const int tid = threadIdx.x;
    const int is64 = *flag;
    const int l  = tid & 63;
    const int w  = tid >> 6;    // wave 0..7
    const int lm = l & 15;      // m/n index within 16x16 tile
    const int g  = l >> 4;      // k-group (frag k0 = 8*g)

    // ---- stage weights once (frag-major) ----
    for (int i = tid; i < 5120; i += 512) {      // WT1: 40 frags x 128 j
        int f = i >> 7, j = i & 127;
        uint4 v = *(const uint4*)(WT1 + (size_t)j * 320 + (f >> 2) * 32 + (f & 3) * 8);
        *(uint4*)(wt1f + (size_t)i * 8) = v;
    }
    for (int i = tid; i < 1024; i += 512) {      // WT2: 16 frags x 64 j
        int f = i >> 6, j = i & 63;
        uint4 v = *(const uint4*)(WT2 + (size_t)j * 128 + (f >> 2) * 32 + (f & 3) * 8);
        *(uint4*)(wt2f + (size_t)i * 8) = v;
    }
    // ---- hoist biases / Wc3 into registers ----
    float bA[8], bB[4], wc3r[16];
#pragma unroll
    for (int n = 0; n < 8; ++n) bA[n] = bc1[16 * n + lm];
#pragma unroll
    for (int n = 0; n < 4; ++n) bB[n] = bc2[16 * n + lm];
    {
        int seg = tid >> 7;
#pragma unroll
        for (int i = 0; i < 16; ++i) wc3r[i] = Wc3[seg * 16 + i];
    }
    const float bc3s = bc3[0];
    const f32x4 zero = {0.f, 0.f, 0.f, 0.f};

    const int T = (E + 127) / 128;
    for (int tile = blockIdx.x; tile < T; tile += gridDim.x) {
        const int tbase = tile * 128;
        __syncthreads();   // prev tile's psum reads done before z1b overwrite

        // ---- gather A-frags: 10 x bf16x8 per lane ----
        const int e  = tbase + 16 * w + lm;
        const int ec = min(e, E - 1);
        const int sE = ld_idx(ei, ec, is64);
        const int dE = ld_idx(ei, (long long)E + ec, is64);
        const unsigned short* rs = h2b + (size_t)sE * 128 + g * 8;
        const unsigned short* rd = h2b + (size_t)dE * 128 + g * 8;
        bf16x8 A[10];
#pragma unroll
        for (int kt = 0; kt < 4; ++kt) A[kt] = *(const bf16x8*)(rs + kt * 32);
#pragma unroll
        for (int kt = 0; kt < 4; ++kt) A[4 + kt] = *(const bf16x8*)(rd + kt * 32);
#pragma unroll
        for (int t = 0; t < 2; ++t) {
            const float* pe = ea + (size_t)ec * 64 + t * 32 + g * 8;
            float4 f0 = *(const float4*)pe;
            float4 f1 = *(const float4*)(pe + 4);
            bf16x8 p;
            p[0] = (short)f2b(f0.x); p[1] = (short)f2b(f0.y);
            p[2] = (short)f2b(f0.z); p[3] = (short)f2b(f0.w);
            p[4] = (short)f2b(f1.x); p[5] = (short)f2b(f1.y);
            p[6] = (short)f2b(f1.z); p[7] = (short)f2b(f1.w);
            A[8 + t] = p;
        }

        // ---- Phase A: z1[128][128], K=320, no barriers ----
        f32x4 acc[8];
#pragma unroll
        for (int n = 0; n < 8; ++n) acc[n] = zero;
#pragma unroll
        for (int kt = 0; kt < 10; ++kt) {
            const unsigned short* wb = wt1f + ((size_t)(kt * 4 + g) * 128) * 8;
#pragma unroll
            for (int n = 0; n < 8; ++n) {
                bf16x8 b = *(const bf16x8*)(wb + (size_t)(16 * n + lm) * 8);
                acc[n] = __builtin_amdgcn_mfma_f32_16x16x32_bf16(A[kt], b, acc[n], 0, 0, 0);
            }
        }
        // epilogue A: bias+ReLU -> z1b (own wave's rows)
#pragma unroll
        for (int n = 0; n < 8; ++n) {
#pragma unroll
            for (int r = 0; r < 4; ++r) {
                float v = fmaxf(acc[n][r] + bA[n], 0.f);
                z1b[(size_t)(16 * w + g * 4 + r) * 136 + 16 * n + lm] = f2b(v);
            }
        }
        __syncthreads();

        // ---- Phase B: z2[128][64], K=128 ----
        f32x4 acc2[4];
#pragma unroll
        for (int n = 0; n < 4; ++n) acc2[n] = zero;
        const unsigned short* brow = z1b + (size_t)(16 * w + lm) * 136;
#pragma unroll
        for (int kt = 0; kt < 4; ++kt) {
            bf16x8 a = *(const bf16x8*)(brow + kt * 32 + g * 8);
            const unsigned short* wb = wt2f + ((size_t)(kt * 4 + g) * 64) * 8;
#pragma unroll
            for (int n = 0; n < 4; ++n) {
                bf16x8 b = *(const bf16x8*)(wb + (size_t)(16 * n + lm) * 8);
                acc2[n] = __builtin_amdgcn_mfma_f32_16x16x32_bf16(a, b, acc2[n], 0, 0, 0);
            }
        }
        __syncthreads();   // z1b reads done before z2b (alias) writes

        // epilogue B: bias+ReLU -> z2b
#pragma unroll
        for (int n = 0; n < 4; ++n) {
#pragma unroll
            for (int r = 0; r < 4; ++r) {
                float v = fmaxf(acc2[n][r] + bB[n], 0.f);
                z2b[(size_t)(16 * w + g * 4 + r) * 72 + 16 * n + lm] = f2b(v);
            }
        }
        __syncthreads();

        // ---- Phase C: psum[e][seg] = dot(z2[e][16seg..16seg+16), wc3r) ----
        {
            int ee = tid & 127, seg = tid >> 7;
            const uint4* zp = (const uint4*)(z2b + (size_t)ee * 72 + seg * 16);
            uint4 v0 = zp[0], v1 = zp[1];
            unsigned int vv[8] = {v0.x, v0.y, v0.z, v0.w, v1.x, v1.y, v1.z, v1.w};
            float p = 0.f;
#pragma unroll
            for (int i = 0; i < 8; ++i) {
                float lo = __builtin_bit_cast(float, vv[i] << 16);
                float hi = __builtin_bit_cast(float, vv[i] & 0xffff0000u);
                p += lo * wc3r[2 * i] + hi * wc3r[2 * i + 1];
            }
            psum[ee * 5 + seg] = p;
        }
        __syncthreads();
        if (tid < 128) {
            float r = psum[tid * 5 + 0] + psum[tid * 5 + 1] + psum[tid * 5 + 2] +
                      psum[tid * 5 + 3] + bc3s;
            if (tbase + tid < E) out[tbase + tid] = r;
        }
    }
}

extern "C" void kernel_launch(void* const* d_in, const int* in_sizes, int n_in,
                              void* d_out, int out_size, void* d_ws,
                              size_t ws_size, hipStream_t stream) {
    const float* x   = (const float*)d_in[0];
    const void*  ei  = d_in[1];
    const float* ea  = (const float*)d_in[2];
    const float* W1  = (const float*)d_in[3];
    const float* b1  = (const float*)d_in[4];
    const float* W2  = (const float*)d_in[5];
    const float* b2  = (const float*)d_in[6];
    const float* Wc1 = (const float*)d_in[7];
    const float* bc1 = (const float*)d_in[8];
    const float* Wc2 = (const float*)d_in[9];
    const float* bc2 = (const float*)d_in[10];
    const float* Wc3 = (const float*)d_in[11];
    const float* bc3 = (const float*)d_in[12];
    float* out = (float*)d_out;

    int N = in_sizes[0] / 16;   // 50000
    int E = in_sizes[2] / 64;   // 800000

    char* ws = (char*)d_ws;
    size_t off = 0;
    auto alloc = [&](size_t bytes) {
        void* p = ws + off;
        off += (bytes + 511) & ~(size_t)511;
        return p;
    };
    int*            cnt    = (int*)alloc((size_t)N * 4);
    int*            cursor = (int*)alloc((size_t)N * 4);
    int*            row    = (int*)alloc((size_t)(N + 1) * 4);
    int*            eids   = (int*)alloc((size_t)E * 4);
    int*            flag   = (int*)alloc(4);
    float*          agg1   = (float*)alloc((size_t)N * 80 * 4);
    float*          h1     = (float*)alloc((size_t)N * 128 * 4);
    float*          agg2   = (float*)alloc((size_t)N * 192 * 4);
    unsigned short* h2b    = (unsigned short*)alloc((size_t)N * 128 * 2);
    unsigned short* WT1    = (unsigned short*)alloc((size_t)128 * 320 * 2);
    unsigned short* WT2    = (unsigned short*)alloc((size_t)64 * 128 * 2);
    (void)ws_size; (void)n_in; (void)out_size;

    hipMemsetAsync(cnt, 0, (size_t)N * 4, stream);
    hipMemsetAsync(cursor, 0, (size_t)N * 4, stream);

    detect64_kernel<<<1, 64, 0, stream>>>(ei, flag);
    prep_w_kernel<<<160, 256, 0, stream>>>(Wc1, Wc2, WT1, WT2);
    hist_kernel<<<1024, 256, 0, stream>>>(ei, E, cnt, flag);
    scan_kernel<<<1, SCAN_T, 0, stream>>>(cnt, row, N);
    fill_kernel<<<1024, 256, 0, stream>>>(ei, E, row, cursor, eids, flag);
    agg1_kernel<<<(N + 3) / 4, 256, 0, stream>>>(ei, x, ea, row, eids, agg1, N, flag);
    update1_kernel<<<(N + 7) / 8, 128, 0, stream>>>(x, agg1, row, W1, b1, h1, N);
    agg2_kernel<<<(N + 3) / 4, 256, 0, stream>>>(ei, h1, ea, row, eids, agg2, N, flag);
    update2_kernel<<<(N + 7) / 8, 128, 0, stream>>>(h1, agg2, row, W2, b2, h2b, N);
    classifier_mfma<<<256, 512, 0, stream>>>(ei, h2b, ea, WT1, bc1,
                                             WT2, bc2, Wc3, bc3,
                                             out, E, flag);
}

// Round 12
// 597.918 us; speedup vs baseline: 5.5935x; 1.2853x over previous
//
#include <hip/hip_runtime.h>

// ---------------------------------------------------------------------------
// E-GraphSAGE forward. Stages:
//   1. CSR build by dst (histogram + scan + fill -> (edge,src) pairs)
//   2. agg1 [N,80]  = sums of [x[src](16) | ea(64)] per dst  (single ea pass)
//   3. h1  [N,128]  = ReLU([x | agg1/deg] @ W1 + b1)
//   4. agg2 [N,128] = sums of h1[src] per dst (ea part reused from agg1)
//   5. h2b [N,128]  = ReLU([h1 | agg2/deg | agg1_ea/deg] @ W2 + b2) -> bf16
//   6. out [E,1]    = edge MLP 320->128->64->1, bf16 MFMA, persistent blocks
// ---------------------------------------------------------------------------

#define SCAN_T 1024

typedef __attribute__((ext_vector_type(8))) short bf16x8;
typedef __attribute__((ext_vector_type(4))) float f32x4;

__device__ __forceinline__ unsigned short f2b(float f) {   // f32 -> bf16 RNE
    unsigned int u = __builtin_bit_cast(unsigned int, f);
    u += 0x7fffu + ((u >> 16) & 1u);
    return (unsigned short)(u >> 16);
}

// edge_index may arrive as int32 or int64 depending on harness conversion.
__device__ __forceinline__ int ld_idx(const void* ei, long long pos, int is64) {
    if (is64) return (int)((const long long*)ei)[pos];
    return ((const int*)ei)[pos];
}

__global__ void detect64_kernel(const void* ei, int* flag) {
    if (threadIdx.x == 0 && blockIdx.x == 0) {
        const int* p = (const int*)ei;
        int is64 = 1;
        for (int i = 0; i < 64; ++i) {
            if (p[2 * i + 1] != 0) { is64 = 0; break; }
        }
        *flag = is64;
    }
}

// Wc1[320][128] -> WT1[128][320] bf16 ; Wc2[128][64] -> WT2[64][128] bf16
__global__ void prep_w_kernel(const float* __restrict__ Wc1,
                              const float* __restrict__ Wc2,
                              unsigned short* __restrict__ WT1,
                              unsigned short* __restrict__ WT2) {
    int i = blockIdx.x * 256 + threadIdx.x;
    if (i < 320 * 128) { int k = i >> 7, n = i & 127; WT1[n * 320 + k] = f2b(Wc1[i]); }
    if (i < 128 * 64)  { int k = i >> 6, n = i & 63;  WT2[n * 128 + k] = f2b(Wc2[i]); }
}

__global__ void hist_kernel(const void* ei, int E, int* cnt, const int* flag) {
    int is64 = *flag;
    for (int e = blockIdx.x * blockDim.x + threadIdx.x; e < E;
         e += gridDim.x * blockDim.x) {
        int d = ld_idx(ei, (long long)E + e, is64);
        atomicAdd(&cnt[d], 1);
    }
}

__global__ void scan_kernel(const int* cnt, int* row, int n) {
    __shared__ int ps[SCAN_T];
    int tid = threadIdx.x;
    int per = (n + SCAN_T - 1) / SCAN_T;
    int s0 = tid * per;
    int s1 = min(s0 + per, n);
    int s = 0;
    for (int i = s0; i < s1; ++i) s += cnt[i];
    ps[tid] = s;
    __syncthreads();
    for (int off = 1; off < SCAN_T; off <<= 1) {
        int v = (tid >= off) ? ps[tid - off] : 0;
        __syncthreads();
        ps[tid] += v;
        __syncthreads();
    }
    int run = (tid == 0) ? 0 : ps[tid - 1];
    for (int i = s0; i < s1; ++i) { row[i] = run; run += cnt[i]; }
    if (s0 < n && s1 == n) row[n] = run;
}

// CSR fill storing (edge, src) pairs: removes one indirection from agg loops.
__global__ void fill_kernel(const void* ei, int E, const int* row, int* cursor,
                            int2* epairs, const int* flag) {
    int is64 = *flag;
    for (int e = blockIdx.x * blockDim.x + threadIdx.x; e < E;
         e += gridDim.x * blockDim.x) {
        int d = ld_idx(ei, (long long)E + e, is64);
        int s = ld_idx(ei, e, is64);
        int pos = atomicAdd(&cursor[d], 1);
        epairs[row[d] + pos] = make_int2(e, s);
    }
}

// agg1[node] = [sum x[src] (16) | sum ea (64)]; one wave/node, unroll-4.
__global__ void agg1_kernel(const int2* __restrict__ ep,
                            const float* __restrict__ x,
                            const float* __restrict__ ea,
                            const int* __restrict__ row,
                            float* __restrict__ agg1, int N) {
    int node = blockIdx.x * 4 + (threadIdx.x >> 6);
    int lane = threadIdx.x & 63;
    if (node >= N) return;
    int r0 = row[node], r1 = row[node + 1];
    float s0 = 0.f, s1 = 0.f, s2 = 0.f, s3 = 0.f, xs = 0.f;
    int i = r0;
    for (; i + 4 <= r1; i += 4) {
        int2 p0 = ep[i], p1 = ep[i + 1], p2 = ep[i + 2], p3 = ep[i + 3];
        float e0 = ea[(size_t)p0.x * 64 + lane];
        float e1 = ea[(size_t)p1.x * 64 + lane];
        float e2 = ea[(size_t)p2.x * 64 + lane];
        float e3 = ea[(size_t)p3.x * 64 + lane];
        if (lane < 16)
            xs += x[p0.y * 16 + lane] + x[p1.y * 16 + lane] +
                  x[p2.y * 16 + lane] + x[p3.y * 16 + lane];
        s0 += e0; s1 += e1; s2 += e2; s3 += e3;
    }
    for (; i < r1; ++i) {
        int2 p = ep[i];
        s0 += ea[(size_t)p.x * 64 + lane];
        if (lane < 16) xs += x[p.y * 16 + lane];
    }
    agg1[node * 80 + 16 + lane] = s0 + s1 + s2 + s3;
    if (lane < 16) agg1[node * 80 + lane] = xs;
}

__global__ void update1_kernel(const float* __restrict__ x,
                               const float* __restrict__ agg1, const int* row,
                               const float* __restrict__ W1,
                               const float* __restrict__ b1,
                               float* __restrict__ h1, int N) {
    __shared__ float in_s[8][96];
    int base = blockIdx.x * 8;
    int tid = threadIdx.x;
    for (int idx = tid; idx < 8 * 96; idx += 128) {
        int i = idx / 96, k = idx % 96;
        int node = base + i;
        float v = 0.f;
        if (node < N) {
            if (k < 16) v = x[node * 16 + k];
            else {
                float inv = 1.f / fmaxf((float)(row[node + 1] - row[node]), 1.f);
                v = agg1[node * 80 + (k - 16)] * inv;
            }
        }
        in_s[i][k] = v;
    }
    __syncthreads();
    int j = tid;
    float acc[8];
#pragma unroll
    for (int i = 0; i < 8; ++i) acc[i] = 0.f;
    for (int k = 0; k < 96; ++k) {
        float w = W1[k * 128 + j];
#pragma unroll
        for (int i = 0; i < 8; ++i) acc[i] += in_s[i][k] * w;
    }
    float bj = b1[j];
#pragma unroll
    for (int i = 0; i < 8; ++i) {
        int node = base + i;
        if (node < N) h1[node * 128 + j] = fmaxf(acc[i] + bj, 0.f);
    }
}

// agg2[node] = sum h1[src] (128); ea part comes from agg1. Unroll-4.
__global__ void agg2_kernel(const int2* __restrict__ ep,
                            const float* __restrict__ h1,
                            const int* __restrict__ row,
                            float* __restrict__ agg2, int N) {
    int node = blockIdx.x * 4 + (threadIdx.x >> 6);
    int lane = threadIdx.x & 63;
    if (node >= N) return;
    int r0 = row[node], r1 = row[node + 1];
    float a0 = 0.f, a1 = 0.f, a2 = 0.f, a3 = 0.f;
    float b0 = 0.f, b1 = 0.f, b2 = 0.f, b3 = 0.f;
    int i = r0;
    for (; i + 4 <= r1; i += 4) {
        int s0 = ep[i].y, s1 = ep[i + 1].y, s2 = ep[i + 2].y, s3 = ep[i + 3].y;
        a0 += h1[(size_t)s0 * 128 + lane];
        a1 += h1[(size_t)s1 * 128 + lane];
        a2 += h1[(size_t)s2 * 128 + lane];
        a3 += h1[(size_t)s3 * 128 + lane];
        b0 += h1[(size_t)s0 * 128 + 64 + lane];
        b1 += h1[(size_t)s1 * 128 + 64 + lane];
        b2 += h1[(size_t)s2 * 128 + 64 + lane];
        b3 += h1[(size_t)s3 * 128 + 64 + lane];
    }
    for (; i < r1; ++i) {
        int s = ep[i].y;
        a0 += h1[(size_t)s * 128 + lane];
        b0 += h1[(size_t)s * 128 + 64 + lane];
    }
    agg2[node * 128 + lane] = a0 + a1 + a2 + a3;
    agg2[node * 128 + 64 + lane] = b0 + b1 + b2 + b3;
}

// h2 written as bf16; ea-mean slice read from agg1.
__global__ void update2_kernel(const float* __restrict__ h1,
                               const float* __restrict__ agg2,
                               const float* __restrict__ agg1, const int* row,
                               const float* __restrict__ W2,
                               const float* __restrict__ b2,
                               unsigned short* __restrict__ h2b, int N) {
    __shared__ float in_s[8][320];
    int base = blockIdx.x * 8;
    int tid = threadIdx.x;
    for (int idx = tid; idx < 8 * 320; idx += 128) {
        int i = idx / 320, k = idx % 320;
        int node = base + i;
        float v = 0.f;
        if (node < N) {
            if (k < 128) v = h1[node * 128 + k];
            else {
                float inv = 1.f / fmaxf((float)(row[node + 1] - row[node]), 1.f);
                if (k < 256) v = agg2[node * 128 + (k - 128)] * inv;
                else         v = agg1[node * 80 + 16 + (k - 256)] * inv;
            }
        }
        in_s[i][k] = v;
    }
    __syncthreads();
    int j = tid;
    float acc[8];
#pragma unroll
    for (int i = 0; i < 8; ++i) acc[i] = 0.f;
    for (int k = 0; k < 320; ++k) {
        float w = W2[k * 128 + j];
#pragma unroll
        for (int i = 0; i < 8; ++i) acc[i] += in_s[i][k] * w;
    }
    float bj = b2[j];
#pragma unroll
    for (int i = 0; i < 8; ++i) {
        int node = base + i;
        if (node < N) h2b[node * 128 + j] = f2b(fmaxf(acc[i] + bj, 0.f));
    }
}

// ---------------------------------------------------------------------------
// Persistent MFMA edge classifier (validated R11). 256 blocks x 512 threads.
// ---------------------------------------------------------------------------
__global__ __launch_bounds__(512, 1) void classifier_mfma(
    const void* ei, const unsigned short* __restrict__ h2b,
    const float* __restrict__ ea,
    const unsigned short* __restrict__ WT1, const float* __restrict__ bc1,
    const unsigned short* __restrict__ WT2, const float* __restrict__ bc2,
    const float* __restrict__ Wc3, const float* __restrict__ bc3,
    float* __restrict__ out, int E, const int* flag) {
    __shared__ __align__(16) char smem[133120];
    unsigned short* wt1f = (unsigned short*)smem;             // 40 frags x 128 j
    unsigned short* wt2f = (unsigned short*)(smem + 81920);   // 16 frags x 64 j
    unsigned short* z1b  = (unsigned short*)(smem + 98304);   // [128][136]
    unsigned short* z2b  = (unsigned short*)(smem + 98304);   // [128][72] alias
    float*          psum = (float*)(smem + 98304 + 18432);    // [128][5]

    const int tid = threadIdx.x;
    const int is64 = *flag;
    const int l  = tid & 63;
    const int w  = tid >> 6;    // wave 0..7
    const int lm = l & 15;      // m/n index within 16x16 tile
    const int g  = l >> 4;      // k-group (frag k0 = 8*g)

    // ---- stage weights once (frag-major) ----
    for (int i = tid; i < 5120; i += 512) {      // WT1: 40 frags x 128 j
        int f = i >> 7, j = i & 127;
        uint4 v = *(const uint4*)(WT1 + (size_t)j * 320 + (f >> 2) * 32 + (f & 3) * 8);
        *(uint4*)(wt1f + (size_t)i * 8) = v;
    }
    for (int i = tid; i < 1024; i += 512) {      // WT2: 16 frags x 64 j
        int f = i >> 6, j = i & 63;
        uint4 v = *(const uint4*)(WT2 + (size_t)j * 128 + (f >> 2) * 32 + (f & 3) * 8);
        *(uint4*)(wt2f + (size_t)i * 8) = v;
    }
    // ---- hoist biases / Wc3 into registers ----
    float bA[8], bB[4], wc3r[16];
#pragma unroll
    for (int n = 0; n < 8; ++n) bA[n] = bc1[16 * n + lm];
#pragma unroll
    for (int n = 0; n < 4; ++n) bB[n] = bc2[16 * n + lm];
    {
        int seg = tid >> 7;
#pragma unroll
        for (int i = 0; i < 16; ++i) wc3r[i] = Wc3[seg * 16 + i];
    }
    const float bc3s = bc3[0];
    const f32x4 zero = {0.f, 0.f, 0.f, 0.f};

    const int T = (E + 127) / 128;
    for (int tile = blockIdx.x; tile < T; tile += gridDim.x) {
        const int tbase = tile * 128;
        __syncthreads();   // prev tile's psum reads done before z1b overwrite

        // ---- gather A-frags: 10 x bf16x8 per lane ----
        const int e  = tbase + 16 * w + lm;
        const int ec = min(e, E - 1);
        const int sE = ld_idx(ei, ec, is64);
        const int dE = ld_idx(ei, (long long)E + ec, is64);
        const unsigned short* rs = h2b + (size_t)sE * 128 + g * 8;
        const unsigned short* rd = h2b + (size_t)dE * 128 + g * 8;
        bf16x8 A[10];
#pragma unroll
        for (int kt = 0; kt < 4; ++kt) A[kt] = *(const bf16x8*)(rs + kt * 32);
#pragma unroll
        for (int kt = 0; kt < 4; ++kt) A[4 + kt] = *(const bf16x8*)(rd + kt * 32);
#pragma unroll
        for (int t = 0; t < 2; ++t) {
            const float* pe = ea + (size_t)ec * 64 + t * 32 + g * 8;
            float4 f0 = *(const float4*)pe;
            float4 f1 = *(const float4*)(pe + 4);
            bf16x8 p;
            p[0] = (short)f2b(f0.x); p[1] = (short)f2b(f0.y);
            p[2] = (short)f2b(f0.z); p[3] = (short)f2b(f0.w);
            p[4] = (short)f2b(f1.x); p[5] = (short)f2b(f1.y);
            p[6] = (short)f2b(f1.z); p[7] = (short)f2b(f1.w);
            A[8 + t] = p;
        }

        // ---- Phase A: z1[128][128], K=320, no barriers ----
        f32x4 acc[8];
#pragma unroll
        for (int n = 0; n < 8; ++n) acc[n] = zero;
#pragma unroll
        for (int kt = 0; kt < 10; ++kt) {
            const unsigned short* wb = wt1f + ((size_t)(kt * 4 + g) * 128) * 8;
#pragma unroll
            for (int n = 0; n < 8; ++n) {
                bf16x8 b = *(const bf16x8*)(wb + (size_t)(16 * n + lm) * 8);
                acc[n] = __builtin_amdgcn_mfma_f32_16x16x32_bf16(A[kt], b, acc[n], 0, 0, 0);
            }
        }
        // epilogue A: bias+ReLU -> z1b (own wave's rows)
#pragma unroll
        for (int n = 0; n < 8; ++n) {
#pragma unroll
            for (int r = 0; r < 4; ++r) {
                float v = fmaxf(acc[n][r] + bA[n], 0.f);
                z1b[(size_t)(16 * w + g * 4 + r) * 136 + 16 * n + lm] = f2b(v);
            }
        }
        __syncthreads();

        // ---- Phase B: z2[128][64], K=128 ----
        f32x4 acc2[4];
#pragma unroll
        for (int n = 0; n < 4; ++n) acc2[n] = zero;
        const unsigned short* brow = z1b + (size_t)(16 * w + lm) * 136;
#pragma unroll
        for (int kt = 0; kt < 4; ++kt) {
            bf16x8 a = *(const bf16x8*)(brow + kt * 32 + g * 8);
            const unsigned short* wb = wt2f + ((size_t)(kt * 4 + g) * 64) * 8;
#pragma unroll
            for (int n = 0; n < 4; ++n) {
                bf16x8 b = *(const bf16x8*)(wb + (size_t)(16 * n + lm) * 8);
                acc2[n] = __builtin_amdgcn_mfma_f32_16x16x32_bf16(a, b, acc2[n], 0, 0, 0);
            }
        }
        __syncthreads();   // z1b reads done before z2b (alias) writes

        // epilogue B: bias+ReLU -> z2b
#pragma unroll
        for (int n = 0; n < 4; ++n) {
#pragma unroll
            for (int r = 0; r < 4; ++r) {
                float v = fmaxf(acc2[n][r] + bB[n], 0.f);
                z2b[(size_t)(16 * w + g * 4 + r) * 72 + 16 * n + lm] = f2b(v);
            }
        }
        __syncthreads();

        // ---- Phase C: psum[e][seg] = dot(z2[e][16seg..16seg+16), wc3r) ----
        {
            int ee = tid & 127, seg = tid >> 7;
            const uint4* zp = (const uint4*)(z2b + (size_t)ee * 72 + seg * 16);
            uint4 v0 = zp[0], v1 = zp[1];
            unsigned int vv[8] = {v0.x, v0.y, v0.z, v0.w, v1.x, v1.y, v1.z, v1.w};
            float p = 0.f;
#pragma unroll
            for (int i = 0; i < 8; ++i) {
                float lo = __builtin_bit_cast(float, vv[i] << 16);
                float hi = __builtin_bit_cast(float, vv[i] & 0xffff0000u);
                p += lo * wc3r[2 * i] + hi * wc3r[2 * i + 1];
            }
            psum[ee * 5 + seg] = p;
        }
        __syncthreads();
        if (tid < 128) {
            float r = psum[tid * 5 + 0] + psum[tid * 5 + 1] + psum[tid * 5 + 2] +
                      psum[tid * 5 + 3] + bc3s;
            if (tbase + tid < E) out[tbase + tid] = r;
        }
    }
}

extern "C" void kernel_launch(void* const* d_in, const int* in_sizes, int n_in,
                              void* d_out, int out_size, void* d_ws,
                              size_t ws_size, hipStream_t stream) {
    const float* x   = (const float*)d_in[0];
    const void*  ei  = d_in[1];
    const float* ea  = (const float*)d_in[2];
    const float* W1  = (const float*)d_in[3];
    const float* b1  = (const float*)d_in[4];
    const float* W2  = (const float*)d_in[5];
    const float* b2  = (const float*)d_in[6];
    const float* Wc1 = (const float*)d_in[7];
    const float* bc1 = (const float*)d_in[8];
    const float* Wc2 = (const float*)d_in[9];
    const float* bc2 = (const float*)d_in[10];
    const float* Wc3 = (const float*)d_in[11];
    const float* bc3 = (const float*)d_in[12];
    float* out = (float*)d_out;

    int N = in_sizes[0] / 16;   // 50000
    int E = in_sizes[2] / 64;   // 800000

    char* ws = (char*)d_ws;
    size_t off = 0;
    auto alloc = [&](size_t bytes) {
        void* p = ws + off;
        off += (bytes + 511) & ~(size_t)511;
        return p;
    };
    int*            cnt    = (int*)alloc((size_t)N * 4);
    int*            cursor = (int*)alloc((size_t)N * 4);
    int*            row    = (int*)alloc((size_t)(N + 1) * 4);
    int2*           epairs = (int2*)alloc((size_t)E * 8);
    int*            flag   = (int*)alloc(4);
    float*          agg1   = (float*)alloc((size_t)N * 80 * 4);
    float*          h1     = (float*)alloc((size_t)N * 128 * 4);
    float*          agg2   = (float*)alloc((size_t)N * 128 * 4);
    unsigned short* h2b    = (unsigned short*)alloc((size_t)N * 128 * 2);
    unsigned short* WT1    = (unsigned short*)alloc((size_t)128 * 320 * 2);
    unsigned short* WT2    = (unsigned short*)alloc((size_t)64 * 128 * 2);
    (void)ws_size; (void)n_in; (void)out_size;

    hipMemsetAsync(cnt, 0, (size_t)N * 4, stream);
    hipMemsetAsync(cursor, 0, (size_t)N * 4, stream);

    detect64_kernel<<<1, 64, 0, stream>>>(ei, flag);
    prep_w_kernel<<<160, 256, 0, stream>>>(Wc1, Wc2, WT1, WT2);
    hist_kernel<<<1024, 256, 0, stream>>>(ei, E, cnt, flag);
    scan_kernel<<<1, SCAN_T, 0, stream>>>(cnt, row, N);
    fill_kernel<<<1024, 256, 0, stream>>>(ei, E, row, cursor, epairs, flag);
    agg1_kernel<<<(N + 3) / 4, 256, 0, stream>>>(epairs, x, ea, row, agg1, N);
    update1_kernel<<<(N + 7) / 8, 128, 0, stream>>>(x, agg1, row, W1, b1, h1, N);
    agg2_kernel<<<(N + 3) / 4, 256, 0, stream>>>(epairs, h1, row, agg2, N);
    update2_kernel<<<(N + 7) / 8, 128, 0, stream>>>(h1, agg2, agg1, row, W2, b2, h2b, N);
    classifier_mfma<<<256, 512, 0, stream>>>(ei, h2b, ea, WT1, bc1,
                                             WT2, bc2, Wc3, bc3,
                                             out, E, flag);
}